// Round 1
// baseline (296.953 us; speedup 1.0000x reference)
//
#include <hip/hip_runtime.h>
#include <hip/hip_bf16.h>

// FuzzyLayer: out[b,s,d*I+i] = exp(-(x[b,s,i]-mu[d,i])^2 / sigma[d,i])
// B=16 S=2048 I=256 D=8. Output 256 MiB fp32 -> memory-bound (~46us floor).

#define BATCH 16
#define SEQ   2048
#define ISIZE 256
#define DEG   8
#define ROWS  (BATCH * SEQ)      // 32768 rows of x
#define ROWQ  (ISIZE / 4)        // 64 float4 per x-row
#define OUTQ  (DEG * ISIZE / 4)  // 512 float4 per out-row

__device__ __forceinline__ float fast_exp2(float v) {
#if __has_builtin(__builtin_amdgcn_exp2f)
    return __builtin_amdgcn_exp2f(v);
#else
    return exp2f(v);
#endif
}

__global__ __launch_bounds__(256) void fuzzy_kernel(
    const float4* __restrict__ x4,
    const float4* __restrict__ fp4,   // (mu,sigma) interleaved pairs, 2048 pairs
    float4* __restrict__ out4)
{
    const int tid    = threadIdx.x;
    const int lane   = tid & 63;   // which float4 chunk of the row (i4 index)
    const int subrow = tid >> 6;   // 0..3 : row slot within the block

    // Per-thread params: 4 consecutive i values x 8 degrees, in registers.
    // fp4[j] covers pairs 2j,2j+1 -> (mu0,s0,mu1,s1).
    const float NLOG2E = -1.4426950408889634f;  // -log2(e)
    float4 mu[DEG], cc[DEG];
#pragma unroll
    for (int d = 0; d < DEG; ++d) {
        float4 p0 = fp4[d * 128 + lane * 2];
        float4 p1 = fp4[d * 128 + lane * 2 + 1];
        mu[d] = make_float4(p0.x, p0.z, p1.x, p1.z);
        cc[d] = make_float4(NLOG2E / p0.y, NLOG2E / p0.w,
                            NLOG2E / p1.y, NLOG2E / p1.w);
    }

    // Grid-stride over groups of 4 rows (one row per 64-lane slot).
    for (int rg = blockIdx.x; rg < ROWS / 4; rg += gridDim.x) {
        const int row = rg * 4 + subrow;
        const float4 xv = x4[row * ROWQ + lane];
        float4* __restrict__ orow = out4 + (size_t)row * OUTQ + lane;
#pragma unroll
        for (int d = 0; d < DEG; ++d) {
            float4 o;
            float t;
            t = xv.x - mu[d].x; o.x = fast_exp2(t * t * cc[d].x);
            t = xv.y - mu[d].y; o.y = fast_exp2(t * t * cc[d].y);
            t = xv.z - mu[d].z; o.z = fast_exp2(t * t * cc[d].z);
            t = xv.w - mu[d].w; o.w = fast_exp2(t * t * cc[d].w);
            orow[d * 64] = o;
        }
    }
}

extern "C" void kernel_launch(void* const* d_in, const int* in_sizes, int n_in,
                              void* d_out, int out_size, void* d_ws, size_t ws_size,
                              hipStream_t stream) {
    const float4* x4  = (const float4*)d_in[0];
    const float4* fp4 = (const float4*)d_in[1];
    float4* out4      = (float4*)d_out;

    dim3 grid(2048);
    dim3 block(256);
    fuzzy_kernel<<<grid, block, 0, stream>>>(x4, fp4, out4);
}

// Round 3
// 294.958 us; speedup vs baseline: 1.0068x; 1.0068x over previous
//
#include <hip/hip_runtime.h>
#include <hip/hip_bf16.h>

// FuzzyLayer: out[b,s,d*I+i] = exp(-(x[b,s,i]-mu[d,i])^2 / sigma[d,i])
// B=16 S=2048 I=256 D=8. Output 268 MB fp32 -> memory(write)-bound.
// R3: R2's nontemporal loads/stores, fixed to use clang ext_vector_type
// (the builtin rejects HIP_vector_type structs).

#define BATCH 16
#define SEQ   2048
#define ISIZE 256
#define DEG   8
#define ROWS  (BATCH * SEQ)      // 32768 rows of x
#define ROWQ  (ISIZE / 4)        // 64 float4 per x-row
#define OUTQ  (DEG * ISIZE / 4)  // 512 float4 per out-row

typedef float f32x4 __attribute__((ext_vector_type(4)));

__device__ __forceinline__ float fast_exp2(float v) {
    return __builtin_amdgcn_exp2f(v);
}
__device__ __forceinline__ float fast_rcp(float v) {
    return __builtin_amdgcn_rcpf(v);
}

__global__ __launch_bounds__(256) void fuzzy_kernel(
    const f32x4* __restrict__ x4,
    const f32x4* __restrict__ fp4,   // (mu,sigma) interleaved pairs, 2048 pairs
    f32x4* __restrict__ out4)
{
    const int tid    = threadIdx.x;
    const int lane   = tid & 63;   // which float4 chunk of the row (i4 index)
    const int subrow = tid >> 6;   // 0..3 : row slot within the block

    // Per-thread params: 4 consecutive i values x 8 degrees, in registers.
    // fp4[j] covers (mu,sigma) pairs 2j,2j+1 -> (mu0,s0,mu1,s1).
    const float NLOG2E = -1.4426950408889634f;  // -log2(e)
    f32x4 mu[DEG], cc[DEG];
#pragma unroll
    for (int d = 0; d < DEG; ++d) {
        f32x4 p0 = fp4[d * 128 + lane * 2];
        f32x4 p1 = fp4[d * 128 + lane * 2 + 1];
        mu[d] = (f32x4){p0.x, p0.z, p1.x, p1.z};
        cc[d] = (f32x4){NLOG2E * fast_rcp(p0.y), NLOG2E * fast_rcp(p0.w),
                        NLOG2E * fast_rcp(p1.y), NLOG2E * fast_rcp(p1.w)};
    }

    // Grid-stride over groups of 4 rows (one row per 64-lane slot).
    for (int rg = blockIdx.x; rg < ROWS / 4; rg += gridDim.x) {
        const int row = rg * 4 + subrow;
        const f32x4 xv = __builtin_nontemporal_load(&x4[row * ROWQ + lane]);
        f32x4* __restrict__ orow = out4 + (size_t)row * OUTQ + lane;
#pragma unroll
        for (int d = 0; d < DEG; ++d) {
            f32x4 o;
            float t;
            t = xv.x - mu[d].x; o.x = fast_exp2(t * t * cc[d].x);
            t = xv.y - mu[d].y; o.y = fast_exp2(t * t * cc[d].y);
            t = xv.z - mu[d].z; o.z = fast_exp2(t * t * cc[d].z);
            t = xv.w - mu[d].w; o.w = fast_exp2(t * t * cc[d].w);
            __builtin_nontemporal_store(o, &orow[d * 64]);
        }
    }
}

extern "C" void kernel_launch(void* const* d_in, const int* in_sizes, int n_in,
                              void* d_out, int out_size, void* d_ws, size_t ws_size,
                              hipStream_t stream) {
    const f32x4* x4  = (const f32x4*)d_in[0];
    const f32x4* fp4 = (const f32x4*)d_in[1];
    f32x4* out4      = (f32x4*)d_out;

    dim3 grid(2048);
    dim3 block(256);
    fuzzy_kernel<<<grid, block, 0, stream>>>(x4, fp4, out4);
}